// Round 5
// baseline (444.968 us; speedup 1.0000x reference)
//
#include <hip/hip_runtime.h>
#include <cstdint>
#include <cstddef>

// Problem constants (B=4, V=64, E=1024, L=1024, D=256, DEG=16)
constexpr int Bv = 4;
constexpr int Ev = 1024;      // edges per batch
constexpr int Lv = 1024;
constexpr int BE = Bv * Ev;   // 4096
constexpr size_t EI_PLANE = (size_t)BE * Lv;  // 4,194,304 elements per ei plane

// bf16 LDS row stride for hs tile: 256 + 8 pad -> 528 B rows (16B aligned;
// b128 fragment reads land 2-way on banks = free)
constexpr int STRB = 264;

typedef __bf16 bf16x8 __attribute__((ext_vector_type(8)));
typedef __bf16 bf16x4 __attribute__((ext_vector_type(4)));
typedef __bf16 bf16x2 __attribute__((ext_vector_type(2)));
typedef float  f32x4  __attribute__((ext_vector_type(4)));

// pack two f32 -> one dword of 2 bf16 (RNE, compiler emits v_cvt_pk_bf16_f32)
static __device__ __forceinline__ unsigned int pack_bf2(float lo, float hi) {
    union { bf16x2 h; unsigned int u; } c;
    c.h[0] = (__bf16)lo; c.h[1] = (__bf16)hi;
    return c.u;
}

// ---------------------------------------------------------------------------
// Precompute (grid 257 x 256 threads):
//  blocks 0..255: tile (i = blk>>4, j = blk&15) of M' = (Wq^T Wk) / 16,
//    bf16, written pre-swizzled to MFMA fragment layout (A- and B-fragment
//    layouts are identical for 16x16x32):
//      for element (d, t):  f = (d>>5)*16 + (t>>4);
//                           lane = ((d>>3)&3)*16 + (t&15); jj = d&7;
//      Mb[(f*64 + lane)*8 + jj] = M'[d][t]
//  block 256: rv[t] = (sum_i bq[i] * Wk[i*256+t]) / 16  (fp32)
//  (bk and the h_src-only bias terms cancel in the softmax -> never computed;
//   the 1/sqrt(D)=1/16 logit scale is folded in here.)
// ---------------------------------------------------------------------------
__global__ __launch_bounds__(256) void precompute_kernel(
    const float* __restrict__ Wq, const float* __restrict__ Wk,
    const float* __restrict__ bq, __bf16* __restrict__ Mb, float* __restrict__ rv)
{
    const int blk = blockIdx.x;
    const int tid = threadIdx.x;
    if (blk < 256) {
        __shared__ float qs[256 * 17];
        __shared__ float ks[256 * 17];
        const int i16 = (blk >> 4) * 16;   // d-tile base
        const int j16 = (blk & 15) * 16;   // t-tile base
        const int c  = tid & 15;
        const int r0 = tid >> 4;
        #pragma unroll
        for (int it = 0; it < 16; ++it) {
            const int r = it * 16 + r0;
            qs[r * 17 + c] = Wq[r * 256 + i16 + c];
            ks[r * 17 + c] = Wk[r * 256 + j16 + c];
        }
        __syncthreads();
        const int dd = tid >> 4;   // 0..15 local d
        const int tt = tid & 15;   // 0..15 local t
        float a0 = 0.f, a1 = 0.f, a2 = 0.f, a3 = 0.f;
        for (int r = 0; r < 256; r += 4) {
            a0 = fmaf(qs[(r + 0) * 17 + dd], ks[(r + 0) * 17 + tt], a0);
            a1 = fmaf(qs[(r + 1) * 17 + dd], ks[(r + 1) * 17 + tt], a1);
            a2 = fmaf(qs[(r + 2) * 17 + dd], ks[(r + 2) * 17 + tt], a2);
            a3 = fmaf(qs[(r + 3) * 17 + dd], ks[(r + 3) * 17 + tt], a3);
        }
        const float m = ((a0 + a1) + (a2 + a3)) * 0.0625f;
        const int d = i16 + dd, t = j16 + tt;
        const int f    = (d >> 5) * 16 + (t >> 4);
        const int lane = ((d >> 3) & 3) * 16 + (t & 15);
        const int jj   = d & 7;
        Mb[((size_t)f * 64 + lane) * 8 + jj] = (__bf16)m;
    } else {
        __shared__ float bqs[256];
        bqs[tid] = bq[tid];
        __syncthreads();
        float a0 = 0.f, a1 = 0.f;
        for (int i = 0; i < 256; i += 2) {
            a0 = fmaf(bqs[i + 0], Wk[(i + 0) * 256 + tid], a0);
            a1 = fmaf(bqs[i + 1], Wk[(i + 1) * 256 + tid], a1);
        }
        rv[tid] = (a0 + a1) * 0.0625f;
    }
}

// ---------------------------------------------------------------------------
// Main fused kernel, 2x2 wave ownership (v-half x t-half), register-resident T.
// One block (4 waves) per (b,l). LDS = hs tile only (33792 B) -> 4 blocks/CU.
// Wave w: vgrp = w>>1 owns S rows [32*vgrp, 32*vgrp+32) (v-tiles vgrp*2,
// vgrp*2+1); thalf = w&1 owns t in [thalf*128, thalf*128+128) (pairs of
// t-tiles p = thalf*4 .. thalf*4+4).
//  1) stage A = hs[b,:,l,:] (64x256) as bf16 in LDS (16B stores); barrier.
//  2) per wave, barrier-free, for each pair p (t-tiles 2p, 2p+1):
//       GEMM1 SWAPPED: acc[tt][mi] = Mb-frag(t-tile) x hs-frag(v-tile)
//         contract d=256: 32 MFMA; lane holds col v, rows t
//       pack f32->bf16 (cvt_pk) + permlane32/16_swap -> GEMM2 A-frag in regs
//       GEMM2 band partial (k-block = pair): s_acc[mi][slot] over n-tiles
//         {m, (m+1)&3}, m = vgrp*2+mi (edge struct: dst in src+1..+16 mod 64)
//     -> s_acc is 16 VGPR (only own rows); Mb read once per wave PAIR
//        (256 KB/block total L2, vs 512 KB for full-t waves)
//  3) barrier; waves thalf==0 store partial S (rows disjoint by vgrp);
//     barrier; waves thalf==1 add their partial; barrier.  (NO big reduce)
//  4) per-edge logits + group-of-16 softmax via shfl; write probs
//     (or scattered ew_out directly if !USE_WS)
// ---------------------------------------------------------------------------
template <bool USE_WS>
__global__ __launch_bounds__(256) void edge_main(
    const float* __restrict__ hs, const int* __restrict__ eidx,
    const float* __restrict__ ew, const float* __restrict__ skipp,
    const __bf16* __restrict__ Mb, const float* __restrict__ rv,
    float* __restrict__ probs_or_out)
{
    __shared__ __bf16 hs_s[64 * STRB];          // 33792 B (only LDS block)
    float* S0 = (float*)hs_s;                   // band-S 64 x 36 f32 (9216 B)
    // (S0 overlays hs_s -- only written after the post-GEMM2 barrier)

    const int bl = blockIdx.x;          // 0..4095
    const int b  = bl >> 10;
    const int l  = bl & 1023;
    const int tid  = threadIdx.x;
    const int w    = tid >> 6;          // wave 0..3
    const int lane = tid & 63;
    const int l15  = lane & 15;
    const int quad = lane >> 4;
    const int vgrp  = w >> 1;           // S row group (rows 32*vgrp ..)
    const int thalf = w & 1;            // t half (t = thalf*128 ..)

    // ---- stage hs tile (64 rows x 256 cols fp32 -> bf16), coalesced ----
    // Each lane owns 8 consecutive floats of one row -> one 16B LDS store.
    {
        const float* base = hs + ((size_t)b * 64 * 1024 + (size_t)l) * 256;
        const int half = lane >> 5;          // 0..1
        const int c8   = (lane & 31) * 8;    // col base
        #pragma unroll
        for (int k = 0; k < 8; ++k) {
            const int v = k * 8 + w * 2 + half;
            const float* p = base + (size_t)v * (1024 * 256) + c8;
            float4 va = *(const float4*)p;
            float4 vb = *(const float4*)(p + 4);
            bf16x8 h;
            h[0] = (__bf16)va.x; h[1] = (__bf16)va.y;
            h[2] = (__bf16)va.z; h[3] = (__bf16)va.w;
            h[4] = (__bf16)vb.x; h[5] = (__bf16)vb.y;
            h[6] = (__bf16)vb.z; h[7] = (__bf16)vb.w;
            *(bf16x8*)(&hs_s[v * STRB + c8]) = h;
        }
    }
    __syncthreads();

    // s_acc[mi][slot]: S rows v-tile (vgrp*2+mi), band n-tiles
    // slot 0 -> n-tile m, slot 1 -> n-tile (m+1)&3   (16 VGPR total)
    f32x4 s_acc[2][2];
    #pragma unroll
    for (int mi = 0; mi < 2; ++mi)
        #pragma unroll
        for (int sl = 0; sl < 2; ++sl) {
            s_acc[mi][sl][0] = 0.f; s_acc[mi][sl][1] = 0.f;
            s_acc[mi][sl][2] = 0.f; s_acc[mi][sl][3] = 0.f;
        }

    const int vt0 = vgrp * 2;            // first owned v-tile (0 or 2)

    #pragma unroll 1
    for (int pp = 0; pp < 4; ++pp) {
        const int p = thalf * 4 + pp;    // t-tile pair index 0..7 (runtime)
        // ---- GEMM1 (swapped): acc[tt][mi], t-tiles {2p, 2p+1} x v-tiles ----
        // bias rv[t] is per-ROW of T^T: element r gets rv[(2p+tt)*16+quad*4+r]
        f32x4 acc[2][2];
        #pragma unroll
        for (int tt = 0; tt < 2; ++tt) {
            const f32x4 rb = *(const f32x4*)(rv + (2 * p + tt) * 16 + quad * 4);
            acc[tt][0] = rb;
            acc[tt][1] = rb;
        }
        #pragma unroll
        for (int kt = 0; kt < 8; ++kt) {
            const bf16x8 mfr0 = *(const bf16x8*)(Mb +
                ((size_t)((kt * 16 + 2 * p + 0) * 64 + lane)) * 8);
            const bf16x8 mfr1 = *(const bf16x8*)(Mb +
                ((size_t)((kt * 16 + 2 * p + 1) * 64 + lane)) * 8);
            #pragma unroll
            for (int mi = 0; mi < 2; ++mi) {
                const bf16x8 hfr = *(const bf16x8*)(
                    &hs_s[((vt0 + mi) * 16 + l15) * STRB + kt * 32 + quad * 8]);
                acc[0][mi] = __builtin_amdgcn_mfma_f32_16x16x32_bf16(
                    mfr0, hfr, acc[0][mi], 0, 0, 0);
                acc[1][mi] = __builtin_amdgcn_mfma_f32_16x16x32_bf16(
                    mfr1, hfr, acc[1][mi], 0, 0, 0);
            }
        }
        // ---- pack + permlane route -> GEMM2 A-frag; band partial S ----
        #pragma unroll
        for (int mi = 0; mi < 2; ++mi) {
            const int m = vt0 + mi;      // global v-tile of these S rows
            unsigned int Ar = pack_bf2(acc[0][mi][0], acc[0][mi][1]); // t=g*4+{0,1}
            unsigned int Br = pack_bf2(acc[0][mi][2], acc[0][mi][3]); // t=g*4+{2,3}
            unsigned int Cr = pack_bf2(acc[1][mi][0], acc[1][mi][1]); // t=16+g*4+{0,1}
            unsigned int Dr = pack_bf2(acc[1][mi][2], acc[1][mi][3]); // t=16+g*4+{2,3}
            asm("v_permlane32_swap_b32 %0, %1" : "+v"(Ar), "+v"(Cr));
            asm("v_permlane16_swap_b32 %0, %1" : "+v"(Ar), "+v"(Cr));
            asm("v_permlane32_swap_b32 %0, %1" : "+v"(Br), "+v"(Dr));
            asm("v_permlane16_swap_b32 %0, %1" : "+v"(Br), "+v"(Dr));
            union { uint4 u; bf16x8 h; } fr;
            fr.u = make_uint4(Ar, Br, Cr, Dr);   // A-frag, k = t-block of pair p
            const bf16x8 brow0 = *(const bf16x8*)(
                &hs_s[(m * 16 + l15) * STRB + p * 32 + quad * 8]);
            const bf16x8 brow1 = *(const bf16x8*)(
                &hs_s[(((m + 1) & 3) * 16 + l15) * STRB + p * 32 + quad * 8]);
            s_acc[mi][0] = __builtin_amdgcn_mfma_f32_16x16x32_bf16(
                fr.h, brow0, s_acc[mi][0], 0, 0, 0);
            s_acc[mi][1] = __builtin_amdgcn_mfma_f32_16x16x32_bf16(
                fr.h, brow1, s_acc[mi][1], 0, 0, 0);
        }
    }
    __syncthreads();   // all waves done reading hs_s -> reuse as S0

    // ---- two-pass partial-S combine (rows disjoint by vgrp) ----
    if (!thalf) {      // waves 0,2: store their t-half partial
        #pragma unroll
        for (int mi = 0; mi < 2; ++mi)
            #pragma unroll
            for (int sl = 0; sl < 2; ++sl)
                #pragma unroll
                for (int r = 0; r < 4; ++r)
                    S0[((vt0 + mi) * 16 + quad * 4 + r) * 36 + sl * 16 + l15] =
                        s_acc[mi][sl][r];
    }
    __syncthreads();
    if (thalf) {       // waves 1,3: add their t-half partial
        #pragma unroll
        for (int mi = 0; mi < 2; ++mi)
            #pragma unroll
            for (int sl = 0; sl < 2; ++sl)
                #pragma unroll
                for (int r = 0; r < 4; ++r)
                    S0[((vt0 + mi) * 16 + quad * 4 + r) * 36 + sl * 16 + l15] +=
                        s_acc[mi][sl][r];
    }
    __syncthreads();

    // ---- per-edge logits + group-of-16 softmax ----
    const int e0  = tid * 4;
    const int be0 = b * Ev + e0;
    int srcs[4], dsts[4];
    #pragma unroll
    for (int j = 0; j < 4; ++j) {
        srcs[j] = eidx[be0 + j];
        dsts[j] = eidx[BE + be0 + j];
    }
    float lg[4];
    #pragma unroll
    for (int j = 0; j < 4; ++j) {
        // dst in {src+1..src+16} mod 64 -> slot in {0,1} always
        const int slot = ((dsts[j] >> 4) - (srcs[j] >> 4)) & 3;
        lg[j] = S0[srcs[j] * 36 + slot * 16 + (dsts[j] & 15)];
    }

    float mx = fmaxf(fmaxf(lg[0], lg[1]), fmaxf(lg[2], lg[3]));
    mx = fmaxf(mx, __shfl_xor(mx, 1));
    mx = fmaxf(mx, __shfl_xor(mx, 2));
    float ex[4], sm = 0.f;
    #pragma unroll
    for (int j = 0; j < 4; ++j) { ex[j] = __expf(lg[j] - mx); sm += ex[j]; }
    sm += __shfl_xor(sm, 1);
    sm += __shfl_xor(sm, 2);
    const float inv = 1.0f / sm;

    if (USE_WS) {
        float4 o = make_float4(ex[0] * inv, ex[1] * inv, ex[2] * inv, ex[3] * inv);
        *(float4*)(probs_or_out + (size_t)bl * 1024 + e0) = o;
    } else {
        const float skip = skipp[0];
        const float om = 1.0f - skip;
        #pragma unroll
        for (int j = 0; j < 4; ++j) {
            float g = fmaf(skip, ew[be0 + j], om * (ex[j] * inv));
            probs_or_out[(size_t)(be0 + j) * Lv + l] = g;
        }
    }
}

// ---------------------------------------------------------------------------
// Output kernel: tiled transpose of probs (b,l,e) -> ew_out (be,l), plus ei
// broadcast. Block = (lt, et, b) transposes one 64x64 tile.
// ---------------------------------------------------------------------------
__global__ __launch_bounds__(256) void output_kernel(
    const float* __restrict__ probs, const int* __restrict__ eidx,
    const float* __restrict__ ew, const float* __restrict__ skipp,
    float* __restrict__ out)
{
    __shared__ float tile[64 * 68];
    const int lt = blockIdx.x;   // 0..15
    const int et = blockIdx.y;   // 0..15
    const int b  = blockIdx.z;   // 0..3
    const int t  = threadIdx.x;
    const int tr = t >> 4;       // 0..15
    const int tc = t & 15;       // 0..15

    #pragma unroll
    for (int q = 0; q < 4; ++q) {
        const int lloc = q * 16 + tr;
        float4 v = *(const float4*)(probs +
            ((size_t)(b * 1024 + lt * 64 + lloc)) * 1024 + et * 64 + tc * 4);
        *(float4*)(&tile[lloc * 68 + tc * 4]) = v;
    }
    __syncthreads();

    const float skip = skipp[0];
    const float om = 1.0f - skip;
    float* out_ei0 = out;
    float* out_ei1 = out + EI_PLANE;
    float* out_ew  = out + 2 * EI_PLANE;

    #pragma unroll
    for (int q = 0; q < 4; ++q) {
        const int eloc = q * 16 + tr;
        const int be = b * Ev + et * 64 + eloc;
        const float w  = ew[be];
        const float sv = (float)eidx[be];
        const float dv = (float)eidx[BE + be];
        const int lloc0 = tc * 4;
        float4 o;
        o.x = fmaf(skip, w, om * tile[(lloc0 + 0) * 68 + eloc]);
        o.y = fmaf(skip, w, om * tile[(lloc0 + 1) * 68 + eloc]);
        o.z = fmaf(skip, w, om * tile[(lloc0 + 2) * 68 + eloc]);
        o.w = fmaf(skip, w, om * tile[(lloc0 + 3) * 68 + eloc]);
        const size_t off = (size_t)be * Lv + lt * 64 + lloc0;
        *(float4*)(out_ew  + off) = o;
        *(float4*)(out_ei0 + off) = make_float4(sv, sv, sv, sv);
        *(float4*)(out_ei1 + off) = make_float4(dv, dv, dv, dv);
    }
}

// Fallback ei broadcast kernel (only used if ws too small for probs buffer)
__global__ __launch_bounds__(256) void ei_kernel(
    const int* __restrict__ eidx, float* __restrict__ out)
{
    const int blk = blockIdx.x;            // 0..8191  (c*4096 + j)
    const int c = blk >> 12;
    const int j = blk & 4095;
    const float v = (float)eidx[c * BE + j];
    float4 o = make_float4(v, v, v, v);
    *(float4*)(out + (size_t)blk * 1024 + threadIdx.x * 4) = o;
}

// ---------------------------------------------------------------------------
extern "C" void kernel_launch(void* const* d_in, const int* in_sizes, int n_in,
                              void* d_out, int out_size, void* d_ws, size_t ws_size,
                              hipStream_t stream)
{
    const float* hs   = (const float*)d_in[0];
    const int*   eidx = (const int*)d_in[1];
    const float* ew   = (const float*)d_in[2];
    const float* Wq   = (const float*)d_in[3];
    const float* bq   = (const float*)d_in[4];
    const float* Wk   = (const float*)d_in[5];
    // d_in[6] = bk: provably unused (cancels in softmax)
    const float* skip = (const float*)d_in[7];

    char* wsb = (char*)d_ws;
    __bf16* Mb   = (__bf16*)wsb;                       // 65536 bf16 = 128 KiB
    float*  rv   = (float*)(wsb + 131072);             // 256 fp32 = 1 KiB
    float*  probs = (float*)(wsb + 132096);            // 4M fp32 = 16 MiB
    const size_t need = 132096 + (size_t)Bv * Lv * Ev * sizeof(float);

    precompute_kernel<<<dim3(257), dim3(256), 0, stream>>>(Wq, Wk, bq, Mb, rv);

    if (ws_size >= need) {
        edge_main<true><<<dim3(Bv * Lv), dim3(256), 0, stream>>>(
            hs, eidx, ew, skip, Mb, rv, probs);
        output_kernel<<<dim3(16, 16, 4), dim3(256), 0, stream>>>(
            probs, eidx, ew, skip, (float*)d_out);
    } else {
        float* out_ew = (float*)d_out + 2 * EI_PLANE;
        edge_main<false><<<dim3(Bv * Lv), dim3(256), 0, stream>>>(
            hs, eidx, ew, skip, Mb, rv, out_ew);
        ei_kernel<<<dim3(2 * BE), dim3(256), 0, stream>>>(eidx, (float*)d_out);
    }
}